// Round 3
// baseline (475.609 us; speedup 1.0000x reference)
//
#include <hip/hip_runtime.h>
#include <hip/hip_bf16.h>
#include <cstdint>
#include <cstddef>

// ---------- kernel 1: materialize combined weight W [128][512] (f32) ----------
// cols 0..127   = w1_0 rows 0..127   (A1)
// cols 128..255 = w2_0 rows 0..127   (A2)
// cols 256..383 = w1_0 rows 128..255 (B1)
// cols 384..511 = w2_0 rows 128..255 (B2)
__global__ void build_w_kernel(const float* __restrict__ w1_0,
                               const float* __restrict__ w2_0,
                               float* __restrict__ W) {
    int idx = blockIdx.x * blockDim.x + threadIdx.x;
    if (idx >= 128 * 512) return;
    int k = idx >> 9;
    int j = idx & 511;
    float v;
    if (j < 128)      v = w1_0[k * 128 + j];
    else if (j < 256) v = w2_0[k * 128 + (j - 128)];
    else if (j < 384) v = w1_0[(128 + k) * 128 + (j - 256)];
    else              v = w2_0[(128 + k) * 128 + (j - 384)];
    W[idx] = v;
}

// ---------- kernel 2: GEMM  C[M,512] = X[M,128](f32) @ W[128,512](f32) ----------
// C cols 0..255 -> SRC[m][0..255] (f32), cols 256..511 -> DST[m][0..255] (f32)
#define GM_BM 64
#define GM_BN 64
#define GM_BK 32
__global__ __launch_bounds__(256) void gemm_precompute(
    const float* __restrict__ X, const float* __restrict__ W,
    float* __restrict__ SRC, float* __restrict__ DST, int M)
{
    __shared__ float sX[GM_BM][GM_BK + 1];
    __shared__ float sW[GM_BK][GM_BN + 1];

    const int tid = threadIdx.x;
    const int bm = blockIdx.x * GM_BM;
    const int bn = blockIdx.y * GM_BN;
    const int ty = tid >> 4;   // 0..15
    const int tx = tid & 15;   // 0..15

    float acc[4][4];
#pragma unroll
    for (int i = 0; i < 4; ++i)
#pragma unroll
        for (int j = 0; j < 4; ++j) acc[i][j] = 0.f;

    for (int kt = 0; kt < 128; kt += GM_BK) {
        // load X tile: 64 rows x 32 cols f32. thread t: row=t/4, 8 cols at (t%4)*8
        {
            int row = tid >> 2;
            int c8 = (tid & 3) * 8;
            int gr = bm + row;
            if (gr < M) {
                const float* xp = X + (size_t)gr * 128 + kt + c8;
                float4 v0 = *(const float4*)xp;
                float4 v1 = *(const float4*)(xp + 4);
                sX[row][c8 + 0] = v0.x; sX[row][c8 + 1] = v0.y;
                sX[row][c8 + 2] = v0.z; sX[row][c8 + 3] = v0.w;
                sX[row][c8 + 4] = v1.x; sX[row][c8 + 5] = v1.y;
                sX[row][c8 + 6] = v1.z; sX[row][c8 + 7] = v1.w;
            } else {
#pragma unroll
                for (int q = 0; q < 8; ++q) sX[row][c8 + q] = 0.f;
            }
        }
        // load W tile: 32 rows x 64 cols f32. two float4 per thread.
        {
            int j4 = (tid & 15) * 4;
#pragma unroll
            for (int r = 0; r < 2; ++r) {
                int kk = r * 16 + (tid >> 4);
                float4 v = *(const float4*)(W + (size_t)(kt + kk) * 512 + bn + j4);
                sW[kk][j4 + 0] = v.x;
                sW[kk][j4 + 1] = v.y;
                sW[kk][j4 + 2] = v.z;
                sW[kk][j4 + 3] = v.w;
            }
        }
        __syncthreads();

#pragma unroll
        for (int k = 0; k < GM_BK; ++k) {
            float a0 = sX[ty * 4 + 0][k];
            float a1 = sX[ty * 4 + 1][k];
            float a2 = sX[ty * 4 + 2][k];
            float a3 = sX[ty * 4 + 3][k];
            float b0 = sW[k][tx * 4 + 0];
            float b1 = sW[k][tx * 4 + 1];
            float b2 = sW[k][tx * 4 + 2];
            float b3 = sW[k][tx * 4 + 3];
            acc[0][0] = fmaf(a0, b0, acc[0][0]); acc[0][1] = fmaf(a0, b1, acc[0][1]);
            acc[0][2] = fmaf(a0, b2, acc[0][2]); acc[0][3] = fmaf(a0, b3, acc[0][3]);
            acc[1][0] = fmaf(a1, b0, acc[1][0]); acc[1][1] = fmaf(a1, b1, acc[1][1]);
            acc[1][2] = fmaf(a1, b2, acc[1][2]); acc[1][3] = fmaf(a1, b3, acc[1][3]);
            acc[2][0] = fmaf(a2, b0, acc[2][0]); acc[2][1] = fmaf(a2, b1, acc[2][1]);
            acc[2][2] = fmaf(a2, b2, acc[2][2]); acc[2][3] = fmaf(a2, b3, acc[2][3]);
            acc[3][0] = fmaf(a3, b0, acc[3][0]); acc[3][1] = fmaf(a3, b1, acc[3][1]);
            acc[3][2] = fmaf(a3, b2, acc[3][2]); acc[3][3] = fmaf(a3, b3, acc[3][3]);
        }
        __syncthreads();
    }

    // store float4 per row-chunk: cols [bn+tx*4, bn+tx*4+4)
    const int c0 = bn + tx * 4;
#pragma unroll
    for (int i = 0; i < 4; ++i) {
        int gr = bm + ty * 4 + i;
        if (gr >= M) continue;
        float4 v = make_float4(acc[i][0], acc[i][1], acc[i][2], acc[i][3]);
        if (c0 < 256) {
            *(float4*)(SRC + (size_t)gr * 256 + c0) = v;
        } else {
            *(float4*)(DST + (size_t)gr * 256 + (c0 - 256)) = v;
        }
    }
}

// ---------- kernel 3: per-edge (one wave per edge, grid-strided) ----------
__global__ __launch_bounds__(256) void edge_kernel(
    const int* __restrict__ eidx,                 // [2,E]
    const float* __restrict__ pos,                // [N,3]
    const float* __restrict__ SRC,                // [N,256] = [A1|A2]
    const float* __restrict__ DST,                // [N,256] = [B1|B2]
    const float* __restrict__ w1_0,
    const float* __restrict__ b1_0,
    const float* __restrict__ w1_1,
    const float* __restrict__ b1_1,
    const float* __restrict__ w2_0,
    const float* __restrict__ b2_0,
    const float* __restrict__ w2_1,
    const float* __restrict__ b2_1,
    float* __restrict__ v1, float* __restrict__ v2,
    int E)
{
    const int lane = threadIdx.x & 63;
    const int wid = blockIdx.x * (blockDim.x >> 6) + (threadIdx.x >> 6);
    const int nw = gridDim.x * (blockDim.x >> 6);
    const int j0 = lane * 2;
    const int j1 = lane * 2 + 1;

    // per-lane weight registers (edge-invariant)
    const float w1d0 = w1_0[256 * 128 + j0];
    const float w1d1 = w1_0[256 * 128 + j1];
    const float b100 = b1_0[j0];
    const float b101 = b1_0[j1];
    const float w110 = w1_1[j0];
    const float w111 = w1_1[j1];
    const float w2d0 = w2_0[256 * 128 + j0];
    const float w2d1 = w2_0[256 * 128 + j1];
    const float b200 = b2_0[j0];
    const float b201 = b2_0[j1];
    const float w210 = w2_1[j0];
    const float w211 = w2_1[j1];
    const float b11 = b1_1[0];
    const float b21 = b2_1[0];
    const float inv_cut = 1.0f / 4.5f;

    for (int e = wid; e < E; e += nw) {
        const int s = eidx[e];
        const int d = eidx[E + e];

        const float rx = pos[s * 3 + 0] - pos[d * 3 + 0];
        const float ry = pos[s * 3 + 1] - pos[d * 3 + 1];
        const float rz = pos[s * 3 + 2] - pos[d * 3 + 2];
        const float dist = sqrtf(rx * rx + ry * ry + rz * rz);

        const float2* rS = (const float2*)(SRC + (size_t)s * 256);
        const float2* rD = (const float2*)(DST + (size_t)d * 256);
        const float2 a1 = rS[lane];        // A1[j0], A1[j1]
        const float2 a2 = rS[64 + lane];   // A2[j0], A2[j1]
        const float2 bb1 = rD[lane];       // B1[j0], B1[j1]
        const float2 bb2 = rD[64 + lane];  // B2[j0], B2[j1]

        float m1 = 0.f, m2 = 0.f, h;
        h = a1.x + bb1.x + fmaf(dist, w1d0, b100); m1 = fmaf(fmaxf(h, 0.f), w110, m1);
        h = a1.y + bb1.y + fmaf(dist, w1d1, b101); m1 = fmaf(fmaxf(h, 0.f), w111, m1);
        h = a2.x + bb2.x + fmaf(dist, w2d0, b200); m2 = fmaf(fmaxf(h, 0.f), w210, m2);
        h = a2.y + bb2.y + fmaf(dist, w2d1, b201); m2 = fmaf(fmaxf(h, 0.f), w211, m2);

#pragma unroll
        for (int off = 32; off > 0; off >>= 1) {
            m1 += __shfl_xor(m1, off);
            m2 += __shfl_xor(m2, off);
        }

        const float mes1 = m1 + b11;
        const float mes2 = m2 + b21;

        const float dd = dist * inv_cut;
        const float d2 = dd * dd;
        const float d4 = d2 * d2;
        const float d5 = d4 * dd;
        const float coe = 1.0f - 21.0f * d5 + 35.0f * d5 * dd - 15.0f * d5 * d2;

        const float inv = 1.0f / (dist + 1e-12f);
        const float s1 = coe * mes1 * inv;
        const float s2 = coe * mes2 * inv;

        if (lane < 3) {
            const float r = (lane == 0) ? rx : ((lane == 1) ? ry : rz);
            atomicAdd(&v1[(size_t)s * 3 + lane], r * s1);
            atomicAdd(&v2[(size_t)s * 3 + lane], r * s2);
        }
    }
}

// ---------- kernel 4: Gram-Schmidt per node ----------
__global__ void gram_kernel(const float* __restrict__ v1,
                            const float* __restrict__ v2,
                            float* __restrict__ out, int N) {
    int n = blockIdx.x * blockDim.x + threadIdx.x;
    if (n >= N) return;
    float ax = v1[n * 3 + 0], ay = v1[n * 3 + 1], az = v1[n * 3 + 2];
    float bx = v2[n * 3 + 0], by = v2[n * 3 + 1], bz = v2[n * 3 + 2];

    float na = sqrtf(ax * ax + ay * ay + az * az) + 1e-12f;
    float n1x = ax / na, n1y = ay / na, n1z = az / na;

    float pr = n1x * bx + n1y * by + n1z * bz;
    float px = bx - pr * n1x, py = by - pr * n1y, pz = bz - pr * n1z;
    float np_ = sqrtf(px * px + py * py + pz * pz) + 1e-12f;
    float n2x = px / np_, n2y = py / np_, n2z = pz / np_;

    float n3x = n1y * n2z - n1z * n2y;
    float n3y = n1z * n2x - n1x * n2z;
    float n3z = n1x * n2y - n1y * n2x;

    float* o = out + (size_t)n * 9;
    o[0] = n1x; o[1] = n1y; o[2] = n1z;
    o[3] = n2x; o[4] = n2y; o[5] = n2z;
    o[6] = n3x; o[7] = n3y; o[8] = n3z;
}

extern "C" void kernel_launch(void* const* d_in, const int* in_sizes, int n_in,
                              void* d_out, int out_size, void* d_ws, size_t ws_size,
                              hipStream_t stream) {
    const float* x    = (const float*)d_in[0];
    const float* pos  = (const float*)d_in[1];
    const int*   eidx = (const int*)d_in[2];
    // d_in[3] = batch (unused)
    const float* w1_0 = (const float*)d_in[4];
    const float* b1_0 = (const float*)d_in[5];
    const float* w1_1 = (const float*)d_in[6];
    const float* b1_1 = (const float*)d_in[7];
    const float* w2_0 = (const float*)d_in[8];
    const float* b2_0 = (const float*)d_in[9];
    const float* w2_1 = (const float*)d_in[10];
    const float* b2_1 = (const float*)d_in[11];

    const int N = in_sizes[0] / 128;
    const int E = in_sizes[2] / 2;

    char* ws = (char*)d_ws;
    float* W   = (float*)ws;                         // 128*512*4 = 256 KiB
    float* SRC = (float*)(ws + 128 * 512 * 4);       // N*256 f32
    float* DST = SRC + (size_t)N * 256;              // N*256 f32
    float* v1  = DST + (size_t)N * 256;              // N*3 f32
    float* v2  = v1 + (size_t)N * 3;                 // N*3 f32

    hipMemsetAsync(v1, 0, (size_t)N * 6 * sizeof(float), stream);

    build_w_kernel<<<(128 * 512 + 255) / 256, 256, 0, stream>>>(w1_0, w2_0, W);

    dim3 gg((N + GM_BM - 1) / GM_BM, 512 / GM_BN);
    gemm_precompute<<<gg, 256, 0, stream>>>(x, W, SRC, DST, N);

    edge_kernel<<<4096, 256, 0, stream>>>(eidx, pos, SRC, DST,
                                          w1_0, b1_0, w1_1, b1_1,
                                          w2_0, b2_0, w2_1, b2_1,
                                          v1, v2, E);

    gram_kernel<<<(N + 255) / 256, 256, 0, stream>>>(v1, v2, (float*)d_out, N);
}